// Round 10
// baseline (407.684 us; speedup 1.0000x reference)
//
#include <hip/hip_runtime.h>

#define NN 50000
#define NE 800000
#define SCB 196    // scan blocks (256 elems each)
#define GBX 782    // ceil(NN/64) gemm node-blocks

typedef __attribute__((ext_vector_type(8))) short short8v;
typedef __attribute__((ext_vector_type(4))) float float4v;

__device__ __forceinline__ int uni(int v) { return __builtin_amdgcn_readfirstlane(v); }

// ---------------- CSR build: count, 3-phase scan(+inv), bucket fill ----------------
__global__ void count_kernel(const int* __restrict__ dst, int* __restrict__ cnt) {
    int i = blockIdx.x * blockDim.x + threadIdx.x;
    if (i < NE) atomicAdd(&cnt[dst[i]], 1);
}

__global__ __launch_bounds__(256) void scan1_kernel(const int* __restrict__ cnt,
                                                    int* __restrict__ part) {
    __shared__ int red[256];
    const int t = threadIdx.x;
    const int i = blockIdx.x * 256 + t;
    red[t] = (i < NN) ? cnt[i] : 0;
    __syncthreads();
#pragma unroll
    for (int d = 128; d > 0; d >>= 1) {
        if (t < d) red[t] += red[t + d];
        __syncthreads();
    }
    if (t == 0) part[blockIdx.x] = red[0];
}

__global__ __launch_bounds__(256) void scan2_kernel(int* __restrict__ part) {
    __shared__ int ps[256];
    const int t = threadIdx.x;
    ps[t] = (t < SCB) ? part[t] : 0;
    __syncthreads();
#pragma unroll
    for (int d = 1; d < 256; d <<= 1) {
        int v = (t >= d) ? ps[t - d] : 0;
        __syncthreads();
        ps[t] += v;
        __syncthreads();
    }
    if (t < SCB) part[t] = (t == 0) ? 0 : ps[t - 1];
}

__global__ __launch_bounds__(256) void scan3_kernel(const int* __restrict__ cnt,
                                                    const int* __restrict__ part,
                                                    int* __restrict__ off,
                                                    int* __restrict__ cursor,
                                                    float* __restrict__ inv) {
    __shared__ int ps[256];
    const int t = threadIdx.x;
    const int i = blockIdx.x * 256 + t;
    const int c = (i < NN) ? cnt[i] : 0;
    ps[t] = c;
    __syncthreads();
#pragma unroll
    for (int d = 1; d < 256; d <<= 1) {
        int v = (t >= d) ? ps[t - d] : 0;
        __syncthreads();
        ps[t] += v;
        __syncthreads();
    }
    if (i < NN) {
        const int o = part[blockIdx.x] + ps[t] - c;   // exclusive
        off[i] = o;
        cursor[i] = o;
        inv[i] = 1.0f / (float)max(c, 1);
    }
}

__global__ void fill_kernel(const int* __restrict__ src, const int* __restrict__ dst,
                            int* __restrict__ cursor, int* __restrict__ srcs) {
    int e = blockIdx.x * blockDim.x + threadIdx.x;
    if (e < NE) {
        int p = atomicAdd(&cursor[dst[e]], 1);
        srcs[p] = src[e];
    }
}

// ---------------- pull-gather mean aggregation, one wave per dst node ----------------
// MODE: 0 = out = mean ; 1 = out = relu(pre + mean) ; 2 = out = pre + mean
template<int D, int MODE>
__global__ __launch_bounds__(256) void gather_kernel(
    const float* __restrict__ y, int ys, const int* __restrict__ srcs,
    const int* __restrict__ off, const int* __restrict__ cnt,
    const float* __restrict__ inv, const float* __restrict__ pre, int ps,
    float* __restrict__ out, int os) {
    const int w = (blockIdx.x * blockDim.x + threadIdx.x) >> 6;
    const int lane = threadIdx.x & 63;
    if (w >= NN) return;
    const int o = uni(off[w]);
    const int n = uni(cnt[w]);
    float a0 = 0.0f, a1 = 0.0f;
    int i = 0;
    for (; i + 4 <= n; i += 4) {
        int sv[4];
#pragma unroll
        for (int u = 0; u < 4; ++u) sv[u] = srcs[o + i + u];
#pragma unroll
        for (int u = 0; u < 4; ++u) {
            a0 += y[(size_t)sv[u] * ys + lane];
            if constexpr (D == 128) a1 += y[(size_t)sv[u] * ys + 64 + lane];
        }
    }
    for (; i < n; ++i) {
        int s = srcs[o + i];
        a0 += y[(size_t)s * ys + lane];
        if constexpr (D == 128) a1 += y[(size_t)s * ys + 64 + lane];
    }
    const float iv = inv[w];
    float r0 = a0 * iv;
    if constexpr (MODE != 0) r0 += pre[(size_t)w * ps + lane];
    if constexpr (MODE == 1) r0 = fmaxf(r0, 0.0f);
    out[(size_t)w * os + lane] = r0;
    if constexpr (D == 128) {
        float r1 = a1 * iv;
        if constexpr (MODE != 0) r1 += pre[(size_t)w * ps + 64 + lane];
        if constexpr (MODE == 1) r1 = fmaxf(r1, 0.0f);
        out[(size_t)w * os + 64 + lane] = r1;
    }
}

// ---------------- weight plane build: fp32 -> bf16 hi/lo (truncation split) ----------------
// 5 segments of [128][128]: seg0=[Wl1;Wr1] seg1=[Wl2|Wr2] seg2=Wl3 seg3=Wr3 seg4=[Wl4;Wr4]
struct WSrc { const float* p[8]; };

__global__ __launch_bounds__(256) void wplanes_kernel(WSrc S,
                                                      unsigned short* __restrict__ ph,
                                                      unsigned short* __restrict__ pl) {
    const int e = blockIdx.x * 256 + threadIdx.x;   // 0..16383
    const int seg = blockIdx.y;
    const int row = e >> 7, k = e & 127;
    float x;
    switch (seg) {
        case 0:  x = (row < 64) ? S.p[0][row * 128 + k] : S.p[1][(row - 64) * 128 + k]; break;
        case 1:  x = (k < 64)   ? S.p[2][row * 64 + k]  : S.p[3][row * 64 + (k - 64)];  break;
        case 2:  x = S.p[4][e]; break;
        case 3:  x = S.p[5][e]; break;
        default: x = (row < 64) ? S.p[6][row * 128 + k] : S.p[7][(row - 64) * 128 + k]; break;
    }
    const unsigned u = __float_as_uint(x);
    const float lo = x - __uint_as_float(u & 0xFFFF0000u);
    const int o = seg * 16384 + e;
    ph[o] = (unsigned short)(u >> 16);
    pl[o] = (unsigned short)(__float_as_uint(lo) >> 16);
}

// ---------------- MFMA split-bf16 GEMM ----------------
// out[n][c] = sum_k in[n][k] * Wplane[c][k] (+bias), K=128, 128 cols.
// Block: 4 waves = 2 node-halves x 2 col-halves; block tile 64 nodes x 128 cols.
// Wave: 2x4 frags of 16x16 via mfma_f32_16x16x32_bf16, 3 precision terms.
// No LDS; A split hi/lo in-register from fp32. grid.y selects arg set (merged launches).
struct GOut {
    const unsigned short* Bh; const unsigned short* Bl;
    float* out0; const float* bias0; int os0;
    float* out1; const float* bias1; int os1;
    int relu;
};
struct GOut2 { GOut g[2]; };

__global__ __launch_bounds__(256, 3) void gemm_mfma(const float* __restrict__ in, GOut2 P) {
    const GOut G = P.g[blockIdx.y];
    const int t = threadIdx.x;
    const int lane = t & 63;
    const int wid = t >> 6;
    const int wn = wid & 1;          // node half (32 rows)
    const int wc = wid >> 1;         // col half (64 cols)
    const int l15 = lane & 15;
    const int lk = lane >> 4;        // 0..3 k-octet
    const int nb = (int)blockIdx.x * 64 + wn * 32;

    float* const outp = wc ? G.out1 : G.out0;
    const float* const biasp = wc ? G.bias1 : G.bias0;
    const int os = wc ? G.os1 : G.os0;
    const unsigned short* const Bhp = G.Bh + (size_t)(wc * 64) * 128;
    const unsigned short* const Blp = G.Bl + (size_t)(wc * 64) * 128;
    const ptrdiff_t dlo = Blp - Bhp;

    float4v acc[2][4];
#pragma unroll
    for (int mi = 0; mi < 2; ++mi)
#pragma unroll
        for (int ci = 0; ci < 4; ++ci) acc[mi][ci] = (float4v)0.0f;

    const float* arow[2];
#pragma unroll
    for (int mi = 0; mi < 2; ++mi) {
        int r = nb + mi * 16 + l15;
        if (r > NN - 1) r = NN - 1;
        arow[mi] = in + (size_t)r * 128;
    }
    const unsigned short* brow[4];
#pragma unroll
    for (int ci = 0; ci < 4; ++ci) brow[ci] = Bhp + (size_t)(ci * 16 + l15) * 128;

    for (int ks = 0; ks < 4; ++ks) {
        const int ko = ks * 32 + lk * 8;
        short8v Ah[2], Al[2];
#pragma unroll
        for (int mi = 0; mi < 2; ++mi) {
            const float4v v0 = *reinterpret_cast<const float4v*>(arow[mi] + ko);
            const float4v v1 = *reinterpret_cast<const float4v*>(arow[mi] + ko + 4);
            float xv[8] = {v0.x, v0.y, v0.z, v0.w, v1.x, v1.y, v1.z, v1.w};
            union { unsigned u[4]; short8v s; } H, L;
#pragma unroll
            for (int q = 0; q < 4; ++q) {
                const unsigned u0 = __float_as_uint(xv[2 * q]);
                const unsigned u1 = __float_as_uint(xv[2 * q + 1]);
                const float l0 = xv[2 * q]     - __uint_as_float(u0 & 0xFFFF0000u);
                const float l1 = xv[2 * q + 1] - __uint_as_float(u1 & 0xFFFF0000u);
                H.u[q] = (u1 & 0xFFFF0000u) | (u0 >> 16);
                L.u[q] = (__float_as_uint(l1) & 0xFFFF0000u) | (__float_as_uint(l0) >> 16);
            }
            Ah[mi] = H.s;
            Al[mi] = L.s;
        }
        short8v Bhf[4], Blf[4];
#pragma unroll
        for (int ci = 0; ci < 4; ++ci) {
            Bhf[ci] = *reinterpret_cast<const short8v*>(brow[ci] + ko);
            Blf[ci] = *reinterpret_cast<const short8v*>(brow[ci] + dlo + ko);
        }
#pragma unroll
        for (int mi = 0; mi < 2; ++mi)
#pragma unroll
            for (int ci = 0; ci < 4; ++ci) {
                acc[mi][ci] = __builtin_amdgcn_mfma_f32_16x16x32_bf16(Ah[mi], Bhf[ci], acc[mi][ci], 0, 0, 0);
                acc[mi][ci] = __builtin_amdgcn_mfma_f32_16x16x32_bf16(Ah[mi], Blf[ci], acc[mi][ci], 0, 0, 0);
                acc[mi][ci] = __builtin_amdgcn_mfma_f32_16x16x32_bf16(Al[mi], Bhf[ci], acc[mi][ci], 0, 0, 0);
            }
    }

    // epilogue: C/D map col=lane&15, row=(lane>>4)*4+j
#pragma unroll
    for (int ci = 0; ci < 4; ++ci) {
        const int c = ci * 16 + l15;
        const float b = biasp ? biasp[c] : 0.0f;
#pragma unroll
        for (int mi = 0; mi < 2; ++mi) {
#pragma unroll
            for (int j = 0; j < 4; ++j) {
                const int r = nb + mi * 16 + lk * 4 + j;
                if (r < NN) {
                    float v = acc[mi][ci][j] + b;
                    if (G.relu) v = fmaxf(v, 0.0f);
                    outp[(size_t)r * os + c] = v;
                }
            }
        }
    }
}

extern "C" void kernel_launch(void* const* d_in, const int* in_sizes, int n_in,
                              void* d_out, int out_size, void* d_ws, size_t ws_size,
                              hipStream_t stream) {
    const float* x   = (const float*)d_in[0];
    const int*   eix = (const int*)d_in[1];
    const float* Wl1 = (const float*)d_in[2];
    const float* bl1 = (const float*)d_in[3];
    const float* Wr1 = (const float*)d_in[4];
    const float* Wl2 = (const float*)d_in[5];
    const float* bl2 = (const float*)d_in[6];
    const float* Wr2 = (const float*)d_in[7];
    const float* Wl3 = (const float*)d_in[8];
    const float* bl3 = (const float*)d_in[9];
    const float* Wr3 = (const float*)d_in[10];
    const float* Wl4 = (const float*)d_in[11];
    const float* bl4 = (const float*)d_in[12];
    const float* Wr4 = (const float*)d_in[13];
    float* out = (float*)d_out;

    const int* src = eix;        // edge_index[0]
    const int* dst = eix + NE;   // edge_index[1]

    // workspace layout
    char* ws = (char*)d_ws;
    int*   cnt    = (int*)ws;                        // [NN]
    int*   off    = cnt + NN;                        // [NN]
    int*   cursor = off + NN;                        // [NN]
    float* inv    = (float*)(cursor + NN);           // [NN]
    int*   part   = (int*)(inv + NN);                // [256]
    int*   srcs   = part + 256;                      // [NE]
    unsigned short* ph = (unsigned short*)(srcs + NE);   // [81920]
    unsigned short* pl = ph + 81920;                     // [81920]
    float* HCAT = (float*)(pl + 81920);              // [NN*128]
    float* H2   = HCAT + (size_t)NN * 128;           // [NN*128]
    float* HPRE = H2 + (size_t)NN * 128;             // [NN*128]

    // ---- CSR build ----
    hipMemsetAsync(cnt, 0, NN * sizeof(int), stream);
    count_kernel<<<(NE + 255) / 256, 256, 0, stream>>>(dst, cnt);
    scan1_kernel<<<SCB, 256, 0, stream>>>(cnt, part);
    scan2_kernel<<<1, 256, 0, stream>>>(part);
    scan3_kernel<<<SCB, 256, 0, stream>>>(cnt, part, off, cursor, inv);
    fill_kernel<<<(NE + 255) / 256, 256, 0, stream>>>(src, dst, cursor, srcs);

    // ---- weight bf16 hi/lo planes ----
    {
        WSrc s;
        s.p[0] = Wl1; s.p[1] = Wr1; s.p[2] = Wl2; s.p[3] = Wr2;
        s.p[4] = Wl3; s.p[5] = Wr3; s.p[6] = Wl4; s.p[7] = Wr4;
        wplanes_kernel<<<dim3(64, 5), 256, 0, stream>>>(s, ph, pl);
    }

    // ---- Layer 1: x@[Wl1;Wr1] -> G1(=HPRE, os64), h1pre(=HCAT+64, os128, +bl1) ----
    {
        GOut2 p{};
        p.g[0] = {ph, pl, HPRE, nullptr, 64, HCAT + 64, bl1, 128, 0};
        p.g[1] = p.g[0];
        gemm_mfma<<<dim3(GBX, 1), 256, 0, stream>>>(x, p);
    }
    gather_kernel<64, 1><<<12500, 256, 0, stream>>>(HPRE, 64, srcs, off, cnt, inv,
                                                    HCAT + 64, 128, HCAT + 64, 128);

    // ---- Layer 2: mean into HCAT cols 0..63, then [mean|h1]@[Wl2|Wr2] -> H2 (relu) ----
    gather_kernel<64, 0><<<12500, 256, 0, stream>>>(HCAT + 64, 128, srcs, off, cnt, inv,
                                                    nullptr, 0, HCAT, 128);
    {
        GOut2 p{};
        p.g[0] = {ph + 16384, pl + 16384, H2, bl2, 128, H2 + 64, bl2 + 64, 128, 1};
        p.g[1] = p.g[0];
        gemm_mfma<<<dim3(GBX, 1), 256, 0, stream>>>(HCAT, p);
    }

    // ---- Layer 3 (merged): h2@Wl3 -> G3(=HCAT); h2@Wr3+bl3 -> h3pre(=HPRE) ----
    {
        GOut2 p{};
        p.g[0] = {ph + 2 * 16384, pl + 2 * 16384, HCAT, nullptr, 128, HCAT + 64, nullptr, 128, 0};
        p.g[1] = {ph + 3 * 16384, pl + 3 * 16384, HPRE, bl3, 128, HPRE + 64, bl3 + 64, 128, 0};
        gemm_mfma<<<dim3(GBX, 2), 256, 0, stream>>>(H2, p);
    }
    gather_kernel<128, 1><<<12500, 256, 0, stream>>>(HCAT, 128, srcs, off, cnt, inv,
                                                     HPRE, 128, HPRE, 128);

    // ---- Layer 4: h3@[Wl4;Wr4] -> G1(=HCAT, os64), outpre(=d_out, +bl4) ----
    {
        GOut2 p{};
        p.g[0] = {ph + 4 * 16384, pl + 4 * 16384, HCAT, nullptr, 64, out, bl4, 64, 0};
        p.g[1] = p.g[0];
        gemm_mfma<<<dim3(GBX, 1), 256, 0, stream>>>(HPRE, p);
    }
    gather_kernel<64, 2><<<12500, 256, 0, stream>>>(HCAT, 64, srcs, off, cnt, inv,
                                                    out, 64, out, 64);
}

// Round 11
// 369.553 us; speedup vs baseline: 1.1032x; 1.1032x over previous
//
#include <hip/hip_runtime.h>

#define NN 50000
#define NE 800000
#define SCB 196    // scan blocks (256 elems each)
#define GB 391     // ceil(NN/128) gemm node-blocks

typedef __attribute__((ext_vector_type(8))) short short8v;
typedef __attribute__((ext_vector_type(4))) float float4v;

__device__ __forceinline__ int uni(int v) { return __builtin_amdgcn_readfirstlane(v); }
__device__ __forceinline__ unsigned short f2bf(float f) {
    unsigned u = __float_as_uint(f);
    return (unsigned short)((u + 0x7FFFu + ((u >> 16) & 1u)) >> 16);
}
__device__ __forceinline__ float bf2f(unsigned short h) {
    return __uint_as_float(((unsigned)h) << 16);
}

// ---------------- CSR build: count, 3-phase scan(+inv), bucket fill ----------------
__global__ void count_kernel(const int* __restrict__ dst, int* __restrict__ cnt) {
    int i = blockIdx.x * blockDim.x + threadIdx.x;
    if (i < NE) atomicAdd(&cnt[dst[i]], 1);
}

__global__ __launch_bounds__(256) void scan1_kernel(const int* __restrict__ cnt,
                                                    int* __restrict__ part) {
    __shared__ int red[256];
    const int t = threadIdx.x;
    const int i = blockIdx.x * 256 + t;
    red[t] = (i < NN) ? cnt[i] : 0;
    __syncthreads();
#pragma unroll
    for (int d = 128; d > 0; d >>= 1) {
        if (t < d) red[t] += red[t + d];
        __syncthreads();
    }
    if (t == 0) part[blockIdx.x] = red[0];
}

__global__ __launch_bounds__(256) void scan2_kernel(int* __restrict__ part) {
    __shared__ int ps[256];
    const int t = threadIdx.x;
    ps[t] = (t < SCB) ? part[t] : 0;
    __syncthreads();
#pragma unroll
    for (int d = 1; d < 256; d <<= 1) {
        int v = (t >= d) ? ps[t - d] : 0;
        __syncthreads();
        ps[t] += v;
        __syncthreads();
    }
    if (t < SCB) part[t] = (t == 0) ? 0 : ps[t - 1];
}

__global__ __launch_bounds__(256) void scan3_kernel(const int* __restrict__ cnt,
                                                    const int* __restrict__ part,
                                                    int* __restrict__ off,
                                                    int* __restrict__ cursor,
                                                    float* __restrict__ inv) {
    __shared__ int ps[256];
    const int t = threadIdx.x;
    const int i = blockIdx.x * 256 + t;
    const int c = (i < NN) ? cnt[i] : 0;
    ps[t] = c;
    __syncthreads();
#pragma unroll
    for (int d = 1; d < 256; d <<= 1) {
        int v = (t >= d) ? ps[t - d] : 0;
        __syncthreads();
        ps[t] += v;
        __syncthreads();
    }
    if (i < NN) {
        const int o = part[blockIdx.x] + ps[t] - c;   // exclusive
        off[i] = o;
        cursor[i] = o;
        inv[i] = 1.0f / (float)max(c, 1);
    }
}

__global__ void fill_kernel(const int* __restrict__ src, const int* __restrict__ dst,
                            int* __restrict__ cursor, int* __restrict__ srcs) {
    int e = blockIdx.x * blockDim.x + threadIdx.x;
    if (e < NE) {
        int p = atomicAdd(&cursor[dst[e]], 1);
        srcs[p] = src[e];
    }
}

// ---------------- pull-gather mean aggregation, one wave per dst node ----------------
// MODE: 0 = out = mean ; 1 = out = relu(pre + mean) ; 2 = out = pre + mean
// SRCBF: y is bf16 (D=64: 1 ushort/lane; D=128: ushort2/lane, cols 2l,2l+1)
// DUALB: additionally write bf16 copy of result (D=64 only)
template<int D, int MODE, int SRCBF, int DUALB>
__global__ __launch_bounds__(256) void gather_kernel(
    const void* __restrict__ yv, int ys, const int* __restrict__ srcs,
    const int* __restrict__ off, const int* __restrict__ cnt,
    const float* __restrict__ inv, const float* __restrict__ pre, int ps,
    float* __restrict__ out, int os, unsigned short* __restrict__ outb) {
    const int w = (blockIdx.x * blockDim.x + threadIdx.x) >> 6;
    const int lane = threadIdx.x & 63;
    if (w >= NN) return;
    const int o = uni(off[w]);
    const int n = uni(cnt[w]);
    const float* yf = (const float*)yv;
    const unsigned short* yb = (const unsigned short*)yv;
    float a0 = 0.0f, a1 = 0.0f;
    int i = 0;
    for (; i + 4 <= n; i += 4) {
        int sv[4];
#pragma unroll
        for (int u = 0; u < 4; ++u) sv[u] = srcs[o + i + u];
#pragma unroll
        for (int u = 0; u < 4; ++u) {
            if constexpr (SRCBF) {
                if constexpr (D == 64) {
                    a0 += bf2f(yb[(size_t)sv[u] * ys + lane]);
                } else {
                    const ushort2 v = *reinterpret_cast<const ushort2*>(
                        &yb[(size_t)sv[u] * ys + 2 * lane]);
                    a0 += bf2f(v.x);
                    a1 += bf2f(v.y);
                }
            } else {
                a0 += yf[(size_t)sv[u] * ys + lane];
                if constexpr (D == 128) a1 += yf[(size_t)sv[u] * ys + 64 + lane];
            }
        }
    }
    for (; i < n; ++i) {
        int s = srcs[o + i];
        if constexpr (SRCBF) {
            if constexpr (D == 64) {
                a0 += bf2f(yb[(size_t)s * ys + lane]);
            } else {
                const ushort2 v = *reinterpret_cast<const ushort2*>(
                    &yb[(size_t)s * ys + 2 * lane]);
                a0 += bf2f(v.x);
                a1 += bf2f(v.y);
            }
        } else {
            a0 += yf[(size_t)s * ys + lane];
            if constexpr (D == 128) a1 += yf[(size_t)s * ys + 64 + lane];
        }
    }
    const float iv = inv[w];
    if constexpr (D == 128 && SRCBF) {
        // lane covers columns 2*lane, 2*lane+1
        float r0 = a0 * iv, r1 = a1 * iv;
        if constexpr (MODE != 0) {
            const float2 pv = *reinterpret_cast<const float2*>(&pre[(size_t)w * ps + 2 * lane]);
            r0 += pv.x; r1 += pv.y;
        }
        if constexpr (MODE == 1) { r0 = fmaxf(r0, 0.0f); r1 = fmaxf(r1, 0.0f); }
        float2 sv = {r0, r1};
        *reinterpret_cast<float2*>(&out[(size_t)w * os + 2 * lane]) = sv;
    } else {
        float r0 = a0 * iv;
        if constexpr (MODE != 0) r0 += pre[(size_t)w * ps + lane];
        if constexpr (MODE == 1) r0 = fmaxf(r0, 0.0f);
        out[(size_t)w * os + lane] = r0;
        if constexpr (DUALB) outb[(size_t)w * 64 + lane] = f2bf(r0);
        if constexpr (D == 128 && !SRCBF) {
            float r1 = a1 * iv;
            if constexpr (MODE != 0) r1 += pre[(size_t)w * ps + 64 + lane];
            if constexpr (MODE == 1) r1 = fmaxf(r1, 0.0f);
            out[(size_t)w * os + 64 + lane] = r1;
        }
    }
}

// ---------------- weight plane build: fp32 -> bf16 hi/lo (truncation split) ----------------
// 5 segments of [128][128]: seg0=[Wl1;Wr1] seg1=[Wl2|Wr2] seg2=Wl3 seg3=Wr3 seg4=[Wl4;Wr4]
struct WSrc { const float* p[8]; };

__global__ __launch_bounds__(256) void wplanes_kernel(WSrc S,
                                                      unsigned short* __restrict__ ph,
                                                      unsigned short* __restrict__ pl) {
    const int e = blockIdx.x * 256 + threadIdx.x;   // 0..16383
    const int seg = blockIdx.y;
    const int row = e >> 7, k = e & 127;
    float x;
    switch (seg) {
        case 0:  x = (row < 64) ? S.p[0][row * 128 + k] : S.p[1][(row - 64) * 128 + k]; break;
        case 1:  x = (k < 64)   ? S.p[2][row * 64 + k]  : S.p[3][row * 64 + (k - 64)];  break;
        case 2:  x = S.p[4][e]; break;
        case 3:  x = S.p[5][e]; break;
        default: x = (row < 64) ? S.p[6][row * 128 + k] : S.p[7][(row - 64) * 128 + k]; break;
    }
    const unsigned u = __float_as_uint(x);
    const float lo = x - __uint_as_float(u & 0xFFFF0000u);
    const int o = seg * 16384 + e;
    ph[o] = (unsigned short)(u >> 16);
    pl[o] = (unsigned short)(__float_as_uint(lo) >> 16);
}

// ---------------- MFMA split-bf16 GEMM (R9 geometry: 128 nodes x 128 cols/block) ----------------
// out[n][c] = sum_k in[n][k] * Wplane[c][k] (+bias), K=128.
// Block: 4 waves (2 node-halves x 2 col-halves). Wave: 4x4 frags 16x16x32_bf16,
// 3 precision terms. No LDS. obf: store output as bf16 (RTNE).
__global__ __launch_bounds__(256) void gemm_mfma(
    const float* __restrict__ in,
    const unsigned short* __restrict__ Bh, const unsigned short* __restrict__ Bl,
    float* __restrict__ out0, const float* __restrict__ bias0, int os0, int obf0,
    float* __restrict__ out1, const float* __restrict__ bias1, int os1, int obf1,
    int relu) {
    const int t = threadIdx.x;
    const int lane = t & 63;
    const int wid = t >> 6;
    const int wn = wid & 1;          // node half
    const int wc = wid >> 1;         // col half
    const int l15 = lane & 15;
    const int lk = lane >> 4;        // 0..3 k-octet
    const int nb = (int)blockIdx.x * 128 + wn * 64;

    float* const outp = wc ? out1 : out0;
    const float* const biasp = wc ? bias1 : bias0;
    const int os = wc ? os1 : os0;
    const int obf = wc ? obf1 : obf0;
    const unsigned short* const Bhp = Bh + (size_t)(wc * 64) * 128;
    const unsigned short* const Blp = Bl + (size_t)(wc * 64) * 128;
    const ptrdiff_t dlo = Blp - Bhp;

    float4v acc[4][4];
#pragma unroll
    for (int mi = 0; mi < 4; ++mi)
#pragma unroll
        for (int ci = 0; ci < 4; ++ci) acc[mi][ci] = (float4v)0.0f;

    const float* arow[4];
#pragma unroll
    for (int mi = 0; mi < 4; ++mi) {
        int r = nb + mi * 16 + l15;
        if (r > NN - 1) r = NN - 1;
        arow[mi] = in + (size_t)r * 128;
    }
    const unsigned short* brow[4];
#pragma unroll
    for (int ci = 0; ci < 4; ++ci) brow[ci] = Bhp + (size_t)(ci * 16 + l15) * 128;

    for (int ks = 0; ks < 4; ++ks) {
        const int ko = ks * 32 + lk * 8;
        short8v Ah[4], Al[4];
#pragma unroll
        for (int mi = 0; mi < 4; ++mi) {
            const float4v v0 = *reinterpret_cast<const float4v*>(arow[mi] + ko);
            const float4v v1 = *reinterpret_cast<const float4v*>(arow[mi] + ko + 4);
            float xv[8] = {v0.x, v0.y, v0.z, v0.w, v1.x, v1.y, v1.z, v1.w};
            union { unsigned u[4]; short8v s; } H, L;
#pragma unroll
            for (int q = 0; q < 4; ++q) {
                const unsigned u0 = __float_as_uint(xv[2 * q]);
                const unsigned u1 = __float_as_uint(xv[2 * q + 1]);
                const float l0 = xv[2 * q]     - __uint_as_float(u0 & 0xFFFF0000u);
                const float l1 = xv[2 * q + 1] - __uint_as_float(u1 & 0xFFFF0000u);
                H.u[q] = (u1 & 0xFFFF0000u) | (u0 >> 16);
                L.u[q] = (__float_as_uint(l1) & 0xFFFF0000u) | (__float_as_uint(l0) >> 16);
            }
            Ah[mi] = H.s;
            Al[mi] = L.s;
        }
        short8v Bhf[4], Blf[4];
#pragma unroll
        for (int ci = 0; ci < 4; ++ci) {
            Bhf[ci] = *reinterpret_cast<const short8v*>(brow[ci] + ko);
            Blf[ci] = *reinterpret_cast<const short8v*>(brow[ci] + dlo + ko);
        }
#pragma unroll
        for (int mi = 0; mi < 4; ++mi)
#pragma unroll
            for (int ci = 0; ci < 4; ++ci) {
                acc[mi][ci] = __builtin_amdgcn_mfma_f32_16x16x32_bf16(Ah[mi], Bhf[ci], acc[mi][ci], 0, 0, 0);
                acc[mi][ci] = __builtin_amdgcn_mfma_f32_16x16x32_bf16(Ah[mi], Blf[ci], acc[mi][ci], 0, 0, 0);
                acc[mi][ci] = __builtin_amdgcn_mfma_f32_16x16x32_bf16(Al[mi], Bhf[ci], acc[mi][ci], 0, 0, 0);
            }
    }

    // epilogue: C/D map col=lane&15, row=(lane>>4)*4+j
#pragma unroll
    for (int ci = 0; ci < 4; ++ci) {
        const int c = ci * 16 + l15;
        const float b = biasp ? biasp[c] : 0.0f;
#pragma unroll
        for (int mi = 0; mi < 4; ++mi) {
#pragma unroll
            for (int j = 0; j < 4; ++j) {
                const int r = nb + mi * 16 + lk * 4 + j;
                if (r < NN) {
                    float v = acc[mi][ci][j] + b;
                    if (relu) v = fmaxf(v, 0.0f);
                    if (obf) ((unsigned short*)outp)[(size_t)r * os + c] = f2bf(v);
                    else outp[(size_t)r * os + c] = v;
                }
            }
        }
    }
}

extern "C" void kernel_launch(void* const* d_in, const int* in_sizes, int n_in,
                              void* d_out, int out_size, void* d_ws, size_t ws_size,
                              hipStream_t stream) {
    const float* x   = (const float*)d_in[0];
    const int*   eix = (const int*)d_in[1];
    const float* Wl1 = (const float*)d_in[2];
    const float* bl1 = (const float*)d_in[3];
    const float* Wr1 = (const float*)d_in[4];
    const float* Wl2 = (const float*)d_in[5];
    const float* bl2 = (const float*)d_in[6];
    const float* Wr2 = (const float*)d_in[7];
    const float* Wl3 = (const float*)d_in[8];
    const float* bl3 = (const float*)d_in[9];
    const float* Wr3 = (const float*)d_in[10];
    const float* Wl4 = (const float*)d_in[11];
    const float* bl4 = (const float*)d_in[12];
    const float* Wr4 = (const float*)d_in[13];
    float* out = (float*)d_out;

    const int* src = eix;        // edge_index[0]
    const int* dst = eix + NE;   // edge_index[1]

    // workspace layout
    char* ws = (char*)d_ws;
    int*   cnt    = (int*)ws;                        // [NN]
    int*   off    = cnt + NN;                        // [NN]
    int*   cursor = off + NN;                        // [NN]
    float* inv    = (float*)(cursor + NN);           // [NN]
    int*   part   = (int*)(inv + NN);                // [256]
    int*   srcs   = part + 256;                      // [NE]
    unsigned short* ph = (unsigned short*)(srcs + NE);   // [81920]
    unsigned short* pl = ph + 81920;                     // [81920]
    // bf16 message region: XB1[NN*64] + H1B[NN*64], later aliased by G3B[NN*128]
    unsigned short* XB1 = pl + 81920;
    unsigned short* H1B = XB1 + (size_t)NN * 64;
    unsigned short* G3B = XB1;
    float* HCAT = (float*)(XB1 + (size_t)NN * 128);  // [NN*128] [mean|h1], later G1(L4)
    float* H2   = HCAT + (size_t)NN * 128;           // [NN*128]
    float* HPRE = H2 + (size_t)NN * 128;             // [NN*128] h3pre/h3

    // ---- CSR build ----
    hipMemsetAsync(cnt, 0, NN * sizeof(int), stream);
    count_kernel<<<(NE + 255) / 256, 256, 0, stream>>>(dst, cnt);
    scan1_kernel<<<SCB, 256, 0, stream>>>(cnt, part);
    scan2_kernel<<<1, 256, 0, stream>>>(part);
    scan3_kernel<<<SCB, 256, 0, stream>>>(cnt, part, off, cursor, inv);
    fill_kernel<<<(NE + 255) / 256, 256, 0, stream>>>(src, dst, cursor, srcs);

    // ---- weight bf16 hi/lo planes ----
    {
        WSrc s;
        s.p[0] = Wl1; s.p[1] = Wr1; s.p[2] = Wl2; s.p[3] = Wr2;
        s.p[4] = Wl3; s.p[5] = Wr3; s.p[6] = Wl4; s.p[7] = Wr4;
        wplanes_kernel<<<dim3(64, 5), 256, 0, stream>>>(s, ph, pl);
    }

    // ---- Layer 1: x@[Wl1;Wr1] -> XB1(bf16, os64), h1pre(=HCAT+64, fp32, +bl1) ----
    gemm_mfma<<<GB, 256, 0, stream>>>(x, ph, pl,
                                      (float*)XB1, nullptr, 64, 1,
                                      HCAT + 64, bl1, 128, 0, 0);
    // h1 = relu(h1pre + mean(XB1)); write fp32 HCAT+64 and bf16 H1B
    gather_kernel<64, 1, 1, 1><<<12500, 256, 0, stream>>>(
        XB1, 64, srcs, off, cnt, inv, HCAT + 64, 128, HCAT + 64, 128, H1B);

    // ---- Layer 2: mean(H1B) -> HCAT cols 0..63 fp32; [mean|h1]@[Wl2|Wr2] -> H2 (relu) ----
    gather_kernel<64, 0, 1, 0><<<12500, 256, 0, stream>>>(
        H1B, 64, srcs, off, cnt, inv, nullptr, 0, HCAT, 128, nullptr);
    gemm_mfma<<<GB, 256, 0, stream>>>(HCAT, ph + 16384, pl + 16384,
                                      H2, bl2, 128, 0,
                                      H2 + 64, bl2 + 64, 128, 0, 1);

    // ---- Layer 3: h2@Wl3 -> G3B (bf16); h2@Wr3+bl3 -> h3pre(=HPRE fp32) ----
    gemm_mfma<<<GB, 256, 0, stream>>>(H2, ph + 2 * 16384, pl + 2 * 16384,
                                      (float*)G3B, nullptr, 128, 1,
                                      (float*)(G3B + 64), nullptr, 128, 1, 0);
    gemm_mfma<<<GB, 256, 0, stream>>>(H2, ph + 3 * 16384, pl + 3 * 16384,
                                      HPRE, bl3, 128, 0,
                                      HPRE + 64, bl3 + 64, 128, 0, 0);
    gather_kernel<128, 1, 1, 0><<<12500, 256, 0, stream>>>(
        G3B, 128, srcs, off, cnt, inv, HPRE, 128, HPRE, 128, nullptr);

    // ---- Layer 4 (fp32): h3@[Wl4;Wr4] -> G1(=HCAT, os64), outpre(=d_out, +bl4) ----
    gemm_mfma<<<GB, 256, 0, stream>>>(HPRE, ph + 4 * 16384, pl + 4 * 16384,
                                      HCAT, nullptr, 64, 0,
                                      out, bl4, 64, 0, 0);
    gather_kernel<64, 2, 0, 0><<<12500, 256, 0, stream>>>(
        HCAT, 64, srcs, off, cnt, inv, out, 64, out, 64, nullptr);
}

// Round 12
// 324.581 us; speedup vs baseline: 1.2560x; 1.1386x over previous
//
#include <hip/hip_runtime.h>

#define NN 50000
#define NE 800000
#define GB 391     // ceil(NN/128) gemm node-blocks
#define NBUK 196   // dst buckets (dst>>8)
#define PB 128     // partition blocks
#define CH 6250    // edges per partition block (PB*CH == NE)
#define HLEN (NBUK * PB)       // 25088
#define SAB (HLEN / 256)       // 98 scan blocks

typedef __attribute__((ext_vector_type(8))) short short8v;
typedef __attribute__((ext_vector_type(4))) float float4v;

__device__ __forceinline__ int uni(int v) { return __builtin_amdgcn_readfirstlane(v); }
__device__ __forceinline__ unsigned short f2bf(float f) {
    unsigned u = __float_as_uint(f);
    return (unsigned short)((u + 0x7FFFu + ((u >> 16) & 1u)) >> 16);
}
__device__ __forceinline__ float bf2f(unsigned short h) {
    return __uint_as_float(((unsigned)h) << 16);
}

// ================= radix CSR build =================
// A) per-block bucket histograms (bucket-major table H[k*PB + b])
__global__ __launch_bounds__(256) void hist_kernel(const int* __restrict__ dst,
                                                   int* __restrict__ H) {
    __shared__ int h[NBUK];
    const int t = threadIdx.x;
    const int b = blockIdx.x;
    if (t < NBUK) h[t] = 0;
    __syncthreads();
    const int e0 = b * CH;
    for (int i = t; i < CH; i += 256) {
        int e = e0 + i;
        if (e < NE) atomicAdd(&h[dst[e] >> 8], 1);
    }
    __syncthreads();
    if (t < NBUK) H[t * PB + b] = h[t];
}

// B) 3-phase exclusive scan of H (length HLEN)
__global__ __launch_bounds__(256) void scanA_kernel(const int* __restrict__ a,
                                                    int* __restrict__ part) {
    __shared__ int red[256];
    const int t = threadIdx.x;
    red[t] = a[blockIdx.x * 256 + t];
    __syncthreads();
#pragma unroll
    for (int d = 128; d > 0; d >>= 1) {
        if (t < d) red[t] += red[t + d];
        __syncthreads();
    }
    if (t == 0) part[blockIdx.x] = red[0];
}

__global__ __launch_bounds__(128) void scanB_kernel(int* __restrict__ part) {
    __shared__ int ps[128];
    const int t = threadIdx.x;
    ps[t] = (t < SAB) ? part[t] : 0;
    __syncthreads();
#pragma unroll
    for (int d = 1; d < 128; d <<= 1) {
        int v = (t >= d) ? ps[t - d] : 0;
        __syncthreads();
        ps[t] += v;
        __syncthreads();
    }
    if (t < SAB) part[t] = (t == 0) ? 0 : ps[t - 1];
}

__global__ __launch_bounds__(256) void scanC_kernel(int* __restrict__ a,
                                                    const int* __restrict__ part) {
    __shared__ int ps[256];
    const int t = threadIdx.x;
    const int i = blockIdx.x * 256 + t;
    const int c = a[i];
    ps[t] = c;
    __syncthreads();
#pragma unroll
    for (int d = 1; d < 256; d <<= 1) {
        int v = (t >= d) ? ps[t - d] : 0;
        __syncthreads();
        ps[t] += v;
        __syncthreads();
    }
    a[i] = part[blockIdx.x] + ps[t] - c;   // exclusive
}

// C) partition: scatter packed (src | dstlow<<16) into per-(block,bucket) ranges
__global__ __launch_bounds__(256) void partition_kernel(const int* __restrict__ src,
                                                        const int* __restrict__ dst,
                                                        const int* __restrict__ Hs,
                                                        unsigned* __restrict__ tmp) {
    __shared__ int cur[NBUK];
    const int t = threadIdx.x;
    const int b = blockIdx.x;
    if (t < NBUK) cur[t] = Hs[t * PB + b];
    __syncthreads();
    const int e0 = b * CH;
    for (int i = t; i < CH; i += 256) {
        int e = e0 + i;
        if (e < NE) {
            const int d = dst[e];
            const int k = d >> 8;
            const int pos = atomicAdd(&cur[k], 1);
            tmp[pos] = (unsigned)src[e] | ((unsigned)(d & 255) << 16);
        }
    }
}

// D) finalize: per bucket, dstlow counting-sort; emit off/cnt/inv + srcs
__global__ __launch_bounds__(256) void finalize_kernel(const unsigned* __restrict__ tmp,
                                                       const int* __restrict__ Hs,
                                                       int* __restrict__ off,
                                                       int* __restrict__ cnt,
                                                       float* __restrict__ inv,
                                                       int* __restrict__ srcs) {
    __shared__ int hist[256];
    __shared__ int ps[256];
    __shared__ int cur[256];
    const int t = threadIdx.x;
    const int k = blockIdx.x;
    const int s0 = Hs[k * PB];
    const int end = (k == NBUK - 1) ? NE : Hs[(k + 1) * PB];
    const int m = end - s0;
    hist[t] = 0;
    __syncthreads();
    for (int i = t; i < m; i += 256) {
        atomicAdd(&hist[(tmp[s0 + i] >> 16) & 255], 1);
    }
    __syncthreads();
    const int c = hist[t];
    ps[t] = c;
    __syncthreads();
#pragma unroll
    for (int d = 1; d < 256; d <<= 1) {
        int v = (t >= d) ? ps[t - d] : 0;
        __syncthreads();
        ps[t] += v;
        __syncthreads();
    }
    const int ex = ps[t] - c;
    const int node = k * 256 + t;
    if (node < NN) {
        off[node] = s0 + ex;
        cnt[node] = c;
        inv[node] = 1.0f / (float)max(c, 1);
    }
    cur[t] = s0 + ex;
    __syncthreads();
    for (int i = t; i < m; i += 256) {
        const unsigned u = tmp[s0 + i];
        const int p = atomicAdd(&cur[(u >> 16) & 255], 1);
        srcs[p] = (int)(u & 0xFFFFu);
    }
}

// ================= pull-gather mean aggregation =================
// MODE: 0 = mean ; 1 = relu(pre + mean) ; 2 = pre + mean
// SRCBF: y bf16 (D=64: 1 ushort/lane; D=128: ushort2/lane); DUALB: also write bf16 copy
template<int D, int MODE, int SRCBF, int DUALB>
__global__ __launch_bounds__(256) void gather_kernel(
    const void* __restrict__ yv, int ys, const int* __restrict__ srcs,
    const int* __restrict__ off, const int* __restrict__ cnt,
    const float* __restrict__ inv, const float* __restrict__ pre, int ps,
    float* __restrict__ out, int os, unsigned short* __restrict__ outb) {
    const int w = (blockIdx.x * blockDim.x + threadIdx.x) >> 6;
    const int lane = threadIdx.x & 63;
    if (w >= NN) return;
    const int o = uni(off[w]);
    const int n = uni(cnt[w]);
    const float* yf = (const float*)yv;
    const unsigned short* yb = (const unsigned short*)yv;
    float a0 = 0.0f, a1 = 0.0f;
    int i = 0;
    for (; i + 4 <= n; i += 4) {
        int sv[4];
#pragma unroll
        for (int u = 0; u < 4; ++u) sv[u] = srcs[o + i + u];
#pragma unroll
        for (int u = 0; u < 4; ++u) {
            if constexpr (SRCBF) {
                if constexpr (D == 64) {
                    a0 += bf2f(yb[(size_t)sv[u] * ys + lane]);
                } else {
                    const ushort2 v = *reinterpret_cast<const ushort2*>(
                        &yb[(size_t)sv[u] * ys + 2 * lane]);
                    a0 += bf2f(v.x);
                    a1 += bf2f(v.y);
                }
            } else {
                a0 += yf[(size_t)sv[u] * ys + lane];
                if constexpr (D == 128) a1 += yf[(size_t)sv[u] * ys + 64 + lane];
            }
        }
    }
    for (; i < n; ++i) {
        int s = srcs[o + i];
        if constexpr (SRCBF) {
            if constexpr (D == 64) {
                a0 += bf2f(yb[(size_t)s * ys + lane]);
            } else {
                const ushort2 v = *reinterpret_cast<const ushort2*>(
                    &yb[(size_t)s * ys + 2 * lane]);
                a0 += bf2f(v.x);
                a1 += bf2f(v.y);
            }
        } else {
            a0 += yf[(size_t)s * ys + lane];
            if constexpr (D == 128) a1 += yf[(size_t)s * ys + 64 + lane];
        }
    }
    const float iv = inv[w];
    if constexpr (D == 128 && SRCBF) {
        float r0 = a0 * iv, r1 = a1 * iv;
        if constexpr (MODE != 0) {
            const float2 pv = *reinterpret_cast<const float2*>(&pre[(size_t)w * ps + 2 * lane]);
            r0 += pv.x; r1 += pv.y;
        }
        if constexpr (MODE == 1) { r0 = fmaxf(r0, 0.0f); r1 = fmaxf(r1, 0.0f); }
        float2 sv = {r0, r1};
        *reinterpret_cast<float2*>(&out[(size_t)w * os + 2 * lane]) = sv;
    } else {
        float r0 = a0 * iv;
        if constexpr (MODE != 0) r0 += pre[(size_t)w * ps + lane];
        if constexpr (MODE == 1) r0 = fmaxf(r0, 0.0f);
        out[(size_t)w * os + lane] = r0;
        if constexpr (DUALB) outb[(size_t)w * 64 + lane] = f2bf(r0);
        if constexpr (D == 128 && !SRCBF) {
            float r1 = a1 * iv;
            if constexpr (MODE != 0) r1 += pre[(size_t)w * ps + 64 + lane];
            if constexpr (MODE == 1) r1 = fmaxf(r1, 0.0f);
            out[(size_t)w * os + 64 + lane] = r1;
        }
    }
}

// ================= weight planes: fp32 -> bf16 hi/lo =================
struct WSrc { const float* p[8]; };

__global__ __launch_bounds__(256) void wplanes_kernel(WSrc S,
                                                      unsigned short* __restrict__ ph,
                                                      unsigned short* __restrict__ pl) {
    const int e = blockIdx.x * 256 + threadIdx.x;   // 0..16383
    const int seg = blockIdx.y;
    const int row = e >> 7, k = e & 127;
    float x;
    switch (seg) {
        case 0:  x = (row < 64) ? S.p[0][row * 128 + k] : S.p[1][(row - 64) * 128 + k]; break;
        case 1:  x = (k < 64)   ? S.p[2][row * 64 + k]  : S.p[3][row * 64 + (k - 64)];  break;
        case 2:  x = S.p[4][e]; break;
        case 3:  x = S.p[5][e]; break;
        default: x = (row < 64) ? S.p[6][row * 128 + k] : S.p[7][(row - 64) * 128 + k]; break;
    }
    const unsigned u = __float_as_uint(x);
    const float lo = x - __uint_as_float(u & 0xFFFF0000u);
    const int o = seg * 16384 + e;
    ph[o] = (unsigned short)(u >> 16);
    pl[o] = (unsigned short)(__float_as_uint(lo) >> 16);
}

// ================= MFMA split-bf16 GEMM (128 nodes x 128 cols / block) =================
__global__ __launch_bounds__(256) void gemm_mfma(
    const float* __restrict__ in,
    const unsigned short* __restrict__ Bh, const unsigned short* __restrict__ Bl,
    float* __restrict__ out0, const float* __restrict__ bias0, int os0, int obf0,
    float* __restrict__ out1, const float* __restrict__ bias1, int os1, int obf1,
    int relu) {
    const int t = threadIdx.x;
    const int lane = t & 63;
    const int wid = t >> 6;
    const int wn = wid & 1;
    const int wc = wid >> 1;
    const int l15 = lane & 15;
    const int lk = lane >> 4;
    const int nb = (int)blockIdx.x * 128 + wn * 64;

    float* const outp = wc ? out1 : out0;
    const float* const biasp = wc ? bias1 : bias0;
    const int os = wc ? os1 : os0;
    const int obf = wc ? obf1 : obf0;
    const unsigned short* const Bhp = Bh + (size_t)(wc * 64) * 128;
    const unsigned short* const Blp = Bl + (size_t)(wc * 64) * 128;
    const ptrdiff_t dlo = Blp - Bhp;

    float4v acc[4][4];
#pragma unroll
    for (int mi = 0; mi < 4; ++mi)
#pragma unroll
        for (int ci = 0; ci < 4; ++ci) acc[mi][ci] = (float4v)0.0f;

    const float* arow[4];
#pragma unroll
    for (int mi = 0; mi < 4; ++mi) {
        int r = nb + mi * 16 + l15;
        if (r > NN - 1) r = NN - 1;
        arow[mi] = in + (size_t)r * 128;
    }
    const unsigned short* brow[4];
#pragma unroll
    for (int ci = 0; ci < 4; ++ci) brow[ci] = Bhp + (size_t)(ci * 16 + l15) * 128;

    for (int ks = 0; ks < 4; ++ks) {
        const int ko = ks * 32 + lk * 8;
        short8v Ah[4], Al[4];
#pragma unroll
        for (int mi = 0; mi < 4; ++mi) {
            const float4v v0 = *reinterpret_cast<const float4v*>(arow[mi] + ko);
            const float4v v1 = *reinterpret_cast<const float4v*>(arow[mi] + ko + 4);
            float xv[8] = {v0.x, v0.y, v0.z, v0.w, v1.x, v1.y, v1.z, v1.w};
            union { unsigned u[4]; short8v s; } H, L;
#pragma unroll
            for (int q = 0; q < 4; ++q) {
                const unsigned u0 = __float_as_uint(xv[2 * q]);
                const unsigned u1 = __float_as_uint(xv[2 * q + 1]);
                const float l0 = xv[2 * q]     - __uint_as_float(u0 & 0xFFFF0000u);
                const float l1 = xv[2 * q + 1] - __uint_as_float(u1 & 0xFFFF0000u);
                H.u[q] = (u1 & 0xFFFF0000u) | (u0 >> 16);
                L.u[q] = (__float_as_uint(l1) & 0xFFFF0000u) | (__float_as_uint(l0) >> 16);
            }
            Ah[mi] = H.s;
            Al[mi] = L.s;
        }
        short8v Bhf[4], Blf[4];
#pragma unroll
        for (int ci = 0; ci < 4; ++ci) {
            Bhf[ci] = *reinterpret_cast<const short8v*>(brow[ci] + ko);
            Blf[ci] = *reinterpret_cast<const short8v*>(brow[ci] + dlo + ko);
        }
#pragma unroll
        for (int mi = 0; mi < 4; ++mi)
#pragma unroll
            for (int ci = 0; ci < 4; ++ci) {
                acc[mi][ci] = __builtin_amdgcn_mfma_f32_16x16x32_bf16(Ah[mi], Bhf[ci], acc[mi][ci], 0, 0, 0);
                acc[mi][ci] = __builtin_amdgcn_mfma_f32_16x16x32_bf16(Ah[mi], Blf[ci], acc[mi][ci], 0, 0, 0);
                acc[mi][ci] = __builtin_amdgcn_mfma_f32_16x16x32_bf16(Al[mi], Bhf[ci], acc[mi][ci], 0, 0, 0);
            }
    }

#pragma unroll
    for (int ci = 0; ci < 4; ++ci) {
        const int c = ci * 16 + l15;
        const float b = biasp ? biasp[c] : 0.0f;
#pragma unroll
        for (int mi = 0; mi < 4; ++mi) {
#pragma unroll
            for (int j = 0; j < 4; ++j) {
                const int r = nb + mi * 16 + lk * 4 + j;
                if (r < NN) {
                    float v = acc[mi][ci][j] + b;
                    if (relu) v = fmaxf(v, 0.0f);
                    if (obf) ((unsigned short*)outp)[(size_t)r * os + c] = f2bf(v);
                    else outp[(size_t)r * os + c] = v;
                }
            }
        }
    }
}

extern "C" void kernel_launch(void* const* d_in, const int* in_sizes, int n_in,
                              void* d_out, int out_size, void* d_ws, size_t ws_size,
                              hipStream_t stream) {
    const float* x   = (const float*)d_in[0];
    const int*   eix = (const int*)d_in[1];
    const float* Wl1 = (const float*)d_in[2];
    const float* bl1 = (const float*)d_in[3];
    const float* Wr1 = (const float*)d_in[4];
    const float* Wl2 = (const float*)d_in[5];
    const float* bl2 = (const float*)d_in[6];
    const float* Wr2 = (const float*)d_in[7];
    const float* Wl3 = (const float*)d_in[8];
    const float* bl3 = (const float*)d_in[9];
    const float* Wr3 = (const float*)d_in[10];
    const float* Wl4 = (const float*)d_in[11];
    const float* bl4 = (const float*)d_in[12];
    const float* Wr4 = (const float*)d_in[13];
    float* out = (float*)d_out;

    const int* src = eix;        // edge_index[0]
    const int* dst = eix + NE;   // edge_index[1]

    // workspace layout
    char* ws = (char*)d_ws;
    int*   cnt  = (int*)ws;                          // [NN]
    int*   off  = cnt + NN;                          // [NN]
    float* inv  = (float*)(off + NN);                // [NN]
    int*   Hs   = (int*)(inv + NN);                  // [HLEN]
    int*   part = Hs + HLEN;                         // [SAB]
    int*   srcs = part + 256;                        // [NE]
    unsigned short* ph = (unsigned short*)(srcs + NE);   // [81920]
    unsigned short* pl = ph + 81920;                     // [81920]
    unsigned short* XB1 = pl + 81920;                // [NN*64] bf16 msgs L1
    unsigned short* H1B = XB1 + (size_t)NN * 64;     // [NN*64] bf16 h1
    unsigned short* G3B = XB1;                       // alias [NN*128] bf16 msgs L3
    float* HCAT = (float*)(XB1 + (size_t)NN * 128);  // [NN*128] [mean|h1]; G4B alias
    float* H2   = HCAT + (size_t)NN * 128;           // [NN*128]
    float* HPRE = H2 + (size_t)NN * 128;             // [NN*128] h3pre/h3; tmp alias
    unsigned*       tmp = (unsigned*)HPRE;           // [NE] (CSR build only)
    unsigned short* G4B = (unsigned short*)HCAT;     // [NN*64] bf16 msgs L4

    // ---- radix CSR build ----
    hist_kernel<<<PB, 256, 0, stream>>>(dst, Hs);
    scanA_kernel<<<SAB, 256, 0, stream>>>(Hs, part);
    scanB_kernel<<<1, 128, 0, stream>>>(part);
    scanC_kernel<<<SAB, 256, 0, stream>>>(Hs, part);
    partition_kernel<<<PB, 256, 0, stream>>>(src, dst, Hs, tmp);
    finalize_kernel<<<NBUK, 256, 0, stream>>>(tmp, Hs, off, cnt, inv, srcs);

    // ---- weight bf16 hi/lo planes ----
    {
        WSrc s;
        s.p[0] = Wl1; s.p[1] = Wr1; s.p[2] = Wl2; s.p[3] = Wr2;
        s.p[4] = Wl3; s.p[5] = Wr3; s.p[6] = Wl4; s.p[7] = Wr4;
        wplanes_kernel<<<dim3(64, 5), 256, 0, stream>>>(s, ph, pl);
    }

    // ---- Layer 1: x@[Wl1;Wr1] -> XB1(bf16), h1pre(=HCAT+64 fp32, +bl1) ----
    gemm_mfma<<<GB, 256, 0, stream>>>(x, ph, pl,
                                      (float*)XB1, nullptr, 64, 1,
                                      HCAT + 64, bl1, 128, 0, 0);
    gather_kernel<64, 1, 1, 1><<<12500, 256, 0, stream>>>(
        XB1, 64, srcs, off, cnt, inv, HCAT + 64, 128, HCAT + 64, 128, H1B);

    // ---- Layer 2: mean(H1B) -> HCAT cols 0..63; [mean|h1]@[Wl2|Wr2] -> H2 (relu) ----
    gather_kernel<64, 0, 1, 0><<<12500, 256, 0, stream>>>(
        H1B, 64, srcs, off, cnt, inv, nullptr, 0, HCAT, 128, nullptr);
    gemm_mfma<<<GB, 256, 0, stream>>>(HCAT, ph + 16384, pl + 16384,
                                      H2, bl2, 128, 0,
                                      H2 + 64, bl2 + 64, 128, 0, 1);

    // ---- Layer 3: h2@Wl3 -> G3B (bf16); h2@Wr3+bl3 -> h3pre(=HPRE fp32) ----
    gemm_mfma<<<GB, 256, 0, stream>>>(H2, ph + 2 * 16384, pl + 2 * 16384,
                                      (float*)G3B, nullptr, 128, 1,
                                      (float*)(G3B + 64), nullptr, 128, 1, 0);
    gemm_mfma<<<GB, 256, 0, stream>>>(H2, ph + 3 * 16384, pl + 3 * 16384,
                                      HPRE, bl3, 128, 0,
                                      HPRE + 64, bl3 + 64, 128, 0, 0);
    gather_kernel<128, 1, 1, 0><<<12500, 256, 0, stream>>>(
        G3B, 128, srcs, off, cnt, inv, HPRE, 128, HPRE, 128, nullptr);

    // ---- Layer 4: h3@Wl4 -> G4B (bf16); h3@Wr4+bl4 -> d_out; gather -> out ----
    gemm_mfma<<<GB, 256, 0, stream>>>(HPRE, ph + 4 * 16384, pl + 4 * 16384,
                                      (float*)G4B, nullptr, 64, 1,
                                      out, bl4, 64, 0, 0);
    gather_kernel<64, 2, 1, 0><<<12500, 256, 0, stream>>>(
        G4B, 64, srcs, off, cnt, inv, out, 64, out, 64, nullptr);
}

// Round 13
// 324.221 us; speedup vs baseline: 1.2574x; 1.0011x over previous
//
#include <hip/hip_runtime.h>

#define NN 50000
#define NE 800000
#define GB 391     // ceil(NN/128) gemm node-blocks
#define NBUK 196   // dst buckets (dst>>8)
#define PB 128     // partition blocks
#define CH 6250    // edges per partition block (PB*CH == NE)
#define HLEN (NBUK * PB)       // 25088
#define SAB (HLEN / 256)       // 98 scan blocks

typedef __attribute__((ext_vector_type(8))) short short8v;
typedef __attribute__((ext_vector_type(4))) float float4v;

__device__ __forceinline__ int uni(int v) { return __builtin_amdgcn_readfirstlane(v); }
__device__ __forceinline__ unsigned short f2bf(float f) {
    unsigned u = __float_as_uint(f);
    return (unsigned short)((u + 0x7FFFu + ((u >> 16) & 1u)) >> 16);
}
__device__ __forceinline__ float bf2f(unsigned short h) {
    return __uint_as_float(((unsigned)h) << 16);
}

// ================= radix CSR build =================
__global__ __launch_bounds__(256) void hist_kernel(const int* __restrict__ dst,
                                                   int* __restrict__ H) {
    __shared__ int h[NBUK];
    const int t = threadIdx.x;
    const int b = blockIdx.x;
    if (t < NBUK) h[t] = 0;
    __syncthreads();
    const int e0 = b * CH;
    for (int i = t; i < CH; i += 256) {
        int e = e0 + i;
        if (e < NE) atomicAdd(&h[dst[e] >> 8], 1);
    }
    __syncthreads();
    if (t < NBUK) H[t * PB + b] = h[t];
}

__global__ __launch_bounds__(256) void scanA_kernel(const int* __restrict__ a,
                                                    int* __restrict__ part) {
    __shared__ int red[256];
    const int t = threadIdx.x;
    red[t] = a[blockIdx.x * 256 + t];
    __syncthreads();
#pragma unroll
    for (int d = 128; d > 0; d >>= 1) {
        if (t < d) red[t] += red[t + d];
        __syncthreads();
    }
    if (t == 0) part[blockIdx.x] = red[0];
}

__global__ __launch_bounds__(128) void scanB_kernel(int* __restrict__ part) {
    __shared__ int ps[128];
    const int t = threadIdx.x;
    ps[t] = (t < SAB) ? part[t] : 0;
    __syncthreads();
#pragma unroll
    for (int d = 1; d < 128; d <<= 1) {
        int v = (t >= d) ? ps[t - d] : 0;
        __syncthreads();
        ps[t] += v;
        __syncthreads();
    }
    if (t < SAB) part[t] = (t == 0) ? 0 : ps[t - 1];
}

__global__ __launch_bounds__(256) void scanC_kernel(int* __restrict__ a,
                                                    const int* __restrict__ part) {
    __shared__ int ps[256];
    const int t = threadIdx.x;
    const int i = blockIdx.x * 256 + t;
    const int c = a[i];
    ps[t] = c;
    __syncthreads();
#pragma unroll
    for (int d = 1; d < 256; d <<= 1) {
        int v = (t >= d) ? ps[t - d] : 0;
        __syncthreads();
        ps[t] += v;
        __syncthreads();
    }
    a[i] = part[blockIdx.x] + ps[t] - c;   // exclusive
}

__global__ __launch_bounds__(256) void partition_kernel(const int* __restrict__ src,
                                                        const int* __restrict__ dst,
                                                        const int* __restrict__ Hs,
                                                        unsigned* __restrict__ tmp) {
    __shared__ int cur[NBUK];
    const int t = threadIdx.x;
    const int b = blockIdx.x;
    if (t < NBUK) cur[t] = Hs[t * PB + b];
    __syncthreads();
    const int e0 = b * CH;
    for (int i = t; i < CH; i += 256) {
        int e = e0 + i;
        if (e < NE) {
            const int d = dst[e];
            const int k = d >> 8;
            const int pos = atomicAdd(&cur[k], 1);
            tmp[pos] = (unsigned)src[e] | ((unsigned)(d & 255) << 16);
        }
    }
}

__global__ __launch_bounds__(256) void finalize_kernel(const unsigned* __restrict__ tmp,
                                                       const int* __restrict__ Hs,
                                                       int* __restrict__ off,
                                                       int* __restrict__ cnt,
                                                       float* __restrict__ inv,
                                                       int* __restrict__ srcs) {
    __shared__ int hist[256];
    __shared__ int ps[256];
    __shared__ int cur[256];
    const int t = threadIdx.x;
    const int k = blockIdx.x;
    const int s0 = Hs[k * PB];
    const int end = (k == NBUK - 1) ? NE : Hs[(k + 1) * PB];
    const int m = end - s0;
    hist[t] = 0;
    __syncthreads();
    for (int i = t; i < m; i += 256) {
        atomicAdd(&hist[(tmp[s0 + i] >> 16) & 255], 1);
    }
    __syncthreads();
    const int c = hist[t];
    ps[t] = c;
    __syncthreads();
#pragma unroll
    for (int d = 1; d < 256; d <<= 1) {
        int v = (t >= d) ? ps[t - d] : 0;
        __syncthreads();
        ps[t] += v;
        __syncthreads();
    }
    const int ex = ps[t] - c;
    const int node = k * 256 + t;
    if (node < NN) {
        off[node] = s0 + ex;
        cnt[node] = c;
        inv[node] = 1.0f / (float)max(c, 1);
    }
    cur[t] = s0 + ex;
    __syncthreads();
    for (int i = t; i < m; i += 256) {
        const unsigned u = tmp[s0 + i];
        const int p = atomicAdd(&cur[(u >> 16) & 255], 1);
        srcs[p] = (int)(u & 0xFFFFu);
    }
}

// ================= pull-gather mean aggregation (half-wave per edge) =================
// bf16 source tables only. Lanes 0-31 process even edges, 32-63 odd edges;
// each lane loads ushort2 (D=64) / ushort4 (D=128) -> one VMEM instr covers 2 edges.
// Partial sums combined across halves via shfl_xor(32); half 0 writes.
// MODE: 0 = mean ; 1 = relu(pre + mean) ; 2 = pre + mean. DUALB: extra bf16 copy (D=64).
template<int D, int MODE, int DUALB>
__global__ __launch_bounds__(256) void gather_kernel(
    const unsigned short* __restrict__ yb, int ys, const int* __restrict__ srcs,
    const int* __restrict__ off, const int* __restrict__ cnt,
    const float* __restrict__ inv, const float* __restrict__ pre, int ps,
    float* __restrict__ out, int os, unsigned short* __restrict__ outb) {
    const int w = (blockIdx.x * blockDim.x + threadIdx.x) >> 6;
    const int lane = threadIdx.x & 63;
    if (w >= NN) return;
    const int o = uni(off[w]);
    const int n = uni(cnt[w]);
    const int h = lane >> 5;       // half-wave id
    const int l = lane & 31;

    float a0 = 0.0f, a1 = 0.0f, a2 = 0.0f, a3 = 0.0f;
    int i = 0;
    for (; i + 8 <= n; i += 8) {
        int e0 = srcs[o + i + h];
        int e1 = srcs[o + i + 2 + h];
        int e2 = srcs[o + i + 4 + h];
        int e3 = srcs[o + i + 6 + h];
        if constexpr (D == 64) {
            const ushort2 v0 = *reinterpret_cast<const ushort2*>(&yb[(size_t)e0 * ys + 2 * l]);
            const ushort2 v1 = *reinterpret_cast<const ushort2*>(&yb[(size_t)e1 * ys + 2 * l]);
            const ushort2 v2 = *reinterpret_cast<const ushort2*>(&yb[(size_t)e2 * ys + 2 * l]);
            const ushort2 v3 = *reinterpret_cast<const ushort2*>(&yb[(size_t)e3 * ys + 2 * l]);
            a0 += bf2f(v0.x) + bf2f(v1.x) + bf2f(v2.x) + bf2f(v3.x);
            a1 += bf2f(v0.y) + bf2f(v1.y) + bf2f(v2.y) + bf2f(v3.y);
        } else {
            const ushort4 v0 = *reinterpret_cast<const ushort4*>(&yb[(size_t)e0 * ys + 4 * l]);
            const ushort4 v1 = *reinterpret_cast<const ushort4*>(&yb[(size_t)e1 * ys + 4 * l]);
            const ushort4 v2 = *reinterpret_cast<const ushort4*>(&yb[(size_t)e2 * ys + 4 * l]);
            const ushort4 v3 = *reinterpret_cast<const ushort4*>(&yb[(size_t)e3 * ys + 4 * l]);
            a0 += bf2f(v0.x) + bf2f(v1.x) + bf2f(v2.x) + bf2f(v3.x);
            a1 += bf2f(v0.y) + bf2f(v1.y) + bf2f(v2.y) + bf2f(v3.y);
            a2 += bf2f(v0.z) + bf2f(v1.z) + bf2f(v2.z) + bf2f(v3.z);
            a3 += bf2f(v0.w) + bf2f(v1.w) + bf2f(v2.w) + bf2f(v3.w);
        }
    }
    for (; i + 2 <= n; i += 2) {
        int e = srcs[o + i + h];
        if constexpr (D == 64) {
            const ushort2 v = *reinterpret_cast<const ushort2*>(&yb[(size_t)e * ys + 2 * l]);
            a0 += bf2f(v.x);
            a1 += bf2f(v.y);
        } else {
            const ushort4 v = *reinterpret_cast<const ushort4*>(&yb[(size_t)e * ys + 4 * l]);
            a0 += bf2f(v.x); a1 += bf2f(v.y); a2 += bf2f(v.z); a3 += bf2f(v.w);
        }
    }
    if (i < n && h == 0) {
        int e = srcs[o + i];
        if constexpr (D == 64) {
            const ushort2 v = *reinterpret_cast<const ushort2*>(&yb[(size_t)e * ys + 2 * l]);
            a0 += bf2f(v.x);
            a1 += bf2f(v.y);
        } else {
            const ushort4 v = *reinterpret_cast<const ushort4*>(&yb[(size_t)e * ys + 4 * l]);
            a0 += bf2f(v.x); a1 += bf2f(v.y); a2 += bf2f(v.z); a3 += bf2f(v.w);
        }
    }
    // combine halves
    a0 += __shfl_xor(a0, 32, 64);
    a1 += __shfl_xor(a1, 32, 64);
    if constexpr (D == 128) {
        a2 += __shfl_xor(a2, 32, 64);
        a3 += __shfl_xor(a3, 32, 64);
    }
    if (h != 0) return;

    const float iv = inv[w];
    if constexpr (D == 64) {
        float r0 = a0 * iv, r1 = a1 * iv;
        if constexpr (MODE != 0) {
            const float2 pv = *reinterpret_cast<const float2*>(&pre[(size_t)w * ps + 2 * l]);
            r0 += pv.x; r1 += pv.y;
        }
        if constexpr (MODE == 1) { r0 = fmaxf(r0, 0.0f); r1 = fmaxf(r1, 0.0f); }
        float2 sv = {r0, r1};
        *reinterpret_cast<float2*>(&out[(size_t)w * os + 2 * l]) = sv;
        if constexpr (DUALB) {
            ushort2 bv = {f2bf(r0), f2bf(r1)};
            *reinterpret_cast<ushort2*>(&outb[(size_t)w * 64 + 2 * l]) = bv;
        }
    } else {
        float r0 = a0 * iv, r1 = a1 * iv, r2 = a2 * iv, r3 = a3 * iv;
        if constexpr (MODE != 0) {
            const float4 pv = *reinterpret_cast<const float4*>(&pre[(size_t)w * ps + 4 * l]);
            r0 += pv.x; r1 += pv.y; r2 += pv.z; r3 += pv.w;
        }
        if constexpr (MODE == 1) {
            r0 = fmaxf(r0, 0.0f); r1 = fmaxf(r1, 0.0f);
            r2 = fmaxf(r2, 0.0f); r3 = fmaxf(r3, 0.0f);
        }
        float4 sv = {r0, r1, r2, r3};
        *reinterpret_cast<float4*>(&out[(size_t)w * os + 4 * l]) = sv;
    }
}

// ================= weight planes: fp32 -> bf16 hi/lo =================
struct WSrc { const float* p[8]; };

__global__ __launch_bounds__(256) void wplanes_kernel(WSrc S,
                                                      unsigned short* __restrict__ ph,
                                                      unsigned short* __restrict__ pl) {
    const int e = blockIdx.x * 256 + threadIdx.x;   // 0..16383
    const int seg = blockIdx.y;
    const int row = e >> 7, k = e & 127;
    float x;
    switch (seg) {
        case 0:  x = (row < 64) ? S.p[0][row * 128 + k] : S.p[1][(row - 64) * 128 + k]; break;
        case 1:  x = (k < 64)   ? S.p[2][row * 64 + k]  : S.p[3][row * 64 + (k - 64)];  break;
        case 2:  x = S.p[4][e]; break;
        case 3:  x = S.p[5][e]; break;
        default: x = (row < 64) ? S.p[6][row * 128 + k] : S.p[7][(row - 64) * 128 + k]; break;
    }
    const unsigned u = __float_as_uint(x);
    const float lo = x - __uint_as_float(u & 0xFFFF0000u);
    const int o = seg * 16384 + e;
    ph[o] = (unsigned short)(u >> 16);
    pl[o] = (unsigned short)(__float_as_uint(lo) >> 16);
}

// ================= MFMA split-bf16 GEMM (128 nodes x 128 cols / block) =================
__global__ __launch_bounds__(256) void gemm_mfma(
    const float* __restrict__ in,
    const unsigned short* __restrict__ Bh, const unsigned short* __restrict__ Bl,
    float* __restrict__ out0, const float* __restrict__ bias0, int os0, int obf0,
    float* __restrict__ out1, const float* __restrict__ bias1, int os1, int obf1,
    int relu) {
    const int t = threadIdx.x;
    const int lane = t & 63;
    const int wid = t >> 6;
    const int wn = wid & 1;
    const int wc = wid >> 1;
    const int l15 = lane & 15;
    const int lk = lane >> 4;
    const int nb = (int)blockIdx.x * 128 + wn * 64;

    float* const outp = wc ? out1 : out0;
    const float* const biasp = wc ? bias1 : bias0;
    const int os = wc ? os1 : os0;
    const int obf = wc ? obf1 : obf0;
    const unsigned short* const Bhp = Bh + (size_t)(wc * 64) * 128;
    const unsigned short* const Blp = Bl + (size_t)(wc * 64) * 128;
    const ptrdiff_t dlo = Blp - Bhp;

    float4v acc[4][4];
#pragma unroll
    for (int mi = 0; mi < 4; ++mi)
#pragma unroll
        for (int ci = 0; ci < 4; ++ci) acc[mi][ci] = (float4v)0.0f;

    const float* arow[4];
#pragma unroll
    for (int mi = 0; mi < 4; ++mi) {
        int r = nb + mi * 16 + l15;
        if (r > NN - 1) r = NN - 1;
        arow[mi] = in + (size_t)r * 128;
    }
    const unsigned short* brow[4];
#pragma unroll
    for (int ci = 0; ci < 4; ++ci) brow[ci] = Bhp + (size_t)(ci * 16 + l15) * 128;

    for (int ks = 0; ks < 4; ++ks) {
        const int ko = ks * 32 + lk * 8;
        short8v Ah[4], Al[4];
#pragma unroll
        for (int mi = 0; mi < 4; ++mi) {
            const float4v v0 = *reinterpret_cast<const float4v*>(arow[mi] + ko);
            const float4v v1 = *reinterpret_cast<const float4v*>(arow[mi] + ko + 4);
            float xv[8] = {v0.x, v0.y, v0.z, v0.w, v1.x, v1.y, v1.z, v1.w};
            union { unsigned u[4]; short8v s; } H, L;
#pragma unroll
            for (int q = 0; q < 4; ++q) {
                const unsigned u0 = __float_as_uint(xv[2 * q]);
                const unsigned u1 = __float_as_uint(xv[2 * q + 1]);
                const float l0 = xv[2 * q]     - __uint_as_float(u0 & 0xFFFF0000u);
                const float l1 = xv[2 * q + 1] - __uint_as_float(u1 & 0xFFFF0000u);
                H.u[q] = (u1 & 0xFFFF0000u) | (u0 >> 16);
                L.u[q] = (__float_as_uint(l1) & 0xFFFF0000u) | (__float_as_uint(l0) >> 16);
            }
            Ah[mi] = H.s;
            Al[mi] = L.s;
        }
        short8v Bhf[4], Blf[4];
#pragma unroll
        for (int ci = 0; ci < 4; ++ci) {
            Bhf[ci] = *reinterpret_cast<const short8v*>(brow[ci] + ko);
            Blf[ci] = *reinterpret_cast<const short8v*>(brow[ci] + dlo + ko);
        }
#pragma unroll
        for (int mi = 0; mi < 4; ++mi)
#pragma unroll
            for (int ci = 0; ci < 4; ++ci) {
                acc[mi][ci] = __builtin_amdgcn_mfma_f32_16x16x32_bf16(Ah[mi], Bhf[ci], acc[mi][ci], 0, 0, 0);
                acc[mi][ci] = __builtin_amdgcn_mfma_f32_16x16x32_bf16(Ah[mi], Blf[ci], acc[mi][ci], 0, 0, 0);
                acc[mi][ci] = __builtin_amdgcn_mfma_f32_16x16x32_bf16(Al[mi], Bhf[ci], acc[mi][ci], 0, 0, 0);
            }
    }

#pragma unroll
    for (int ci = 0; ci < 4; ++ci) {
        const int c = ci * 16 + l15;
        const float b = biasp ? biasp[c] : 0.0f;
#pragma unroll
        for (int mi = 0; mi < 4; ++mi) {
#pragma unroll
            for (int j = 0; j < 4; ++j) {
                const int r = nb + mi * 16 + lk * 4 + j;
                if (r < NN) {
                    float v = acc[mi][ci][j] + b;
                    if (relu) v = fmaxf(v, 0.0f);
                    if (obf) ((unsigned short*)outp)[(size_t)r * os + c] = f2bf(v);
                    else outp[(size_t)r * os + c] = v;
                }
            }
        }
    }
}

extern "C" void kernel_launch(void* const* d_in, const int* in_sizes, int n_in,
                              void* d_out, int out_size, void* d_ws, size_t ws_size,
                              hipStream_t stream) {
    const float* x   = (const float*)d_in[0];
    const int*   eix = (const int*)d_in[1];
    const float* Wl1 = (const float*)d_in[2];
    const float* bl1 = (const float*)d_in[3];
    const float* Wr1 = (const float*)d_in[4];
    const float* Wl2 = (const float*)d_in[5];
    const float* bl2 = (const float*)d_in[6];
    const float* Wr2 = (const float*)d_in[7];
    const float* Wl3 = (const float*)d_in[8];
    const float* bl3 = (const float*)d_in[9];
    const float* Wr3 = (const float*)d_in[10];
    const float* Wl4 = (const float*)d_in[11];
    const float* bl4 = (const float*)d_in[12];
    const float* Wr4 = (const float*)d_in[13];
    float* out = (float*)d_out;

    const int* src = eix;        // edge_index[0]
    const int* dst = eix + NE;   // edge_index[1]

    // workspace layout
    char* ws = (char*)d_ws;
    int*   cnt  = (int*)ws;                          // [NN]
    int*   off  = cnt + NN;                          // [NN]
    float* inv  = (float*)(off + NN);                // [NN]
    int*   Hs   = (int*)(inv + NN);                  // [HLEN]
    int*   part = Hs + HLEN;                         // [SAB]
    int*   srcs = part + 256;                        // [NE]
    unsigned short* ph = (unsigned short*)(srcs + NE);   // [81920]
    unsigned short* pl = ph + 81920;                     // [81920]
    unsigned short* XB1 = pl + 81920;                // [NN*64] bf16 msgs L1
    unsigned short* H1B = XB1 + (size_t)NN * 64;     // [NN*64] bf16 h1
    unsigned short* G3B = XB1;                       // alias [NN*128] bf16 msgs L3
    float* HCAT = (float*)(XB1 + (size_t)NN * 128);  // [NN*128] [mean|h1]; G4B alias
    float* H2   = HCAT + (size_t)NN * 128;           // [NN*128]
    float* HPRE = H2 + (size_t)NN * 128;             // [NN*128] h3pre/h3; tmp alias
    unsigned*       tmp = (unsigned*)HPRE;           // [NE] (CSR build only)
    unsigned short* G4B = (unsigned short*)HCAT;     // [NN*64] bf16 msgs L4

    // ---- radix CSR build ----
    hist_kernel<<<PB, 256, 0, stream>>>(dst, Hs);
    scanA_kernel<<<SAB, 256, 0, stream>>>(Hs, part);
    scanB_kernel<<<1, 128, 0, stream>>>(part);
    scanC_kernel<<<SAB, 256, 0, stream>>>(Hs, part);
    partition_kernel<<<PB, 256, 0, stream>>>(src, dst, Hs, tmp);
    finalize_kernel<<<NBUK, 256, 0, stream>>>(tmp, Hs, off, cnt, inv, srcs);

    // ---- weight bf16 hi/lo planes ----
    {
        WSrc s;
        s.p[0] = Wl1; s.p[1] = Wr1; s.p[2] = Wl2; s.p[3] = Wr2;
        s.p[4] = Wl3; s.p[5] = Wr3; s.p[6] = Wl4; s.p[7] = Wr4;
        wplanes_kernel<<<dim3(64, 5), 256, 0, stream>>>(s, ph, pl);
    }

    // ---- Layer 1: x@[Wl1;Wr1] -> XB1(bf16), h1pre(=HCAT+64 fp32, +bl1) ----
    gemm_mfma<<<GB, 256, 0, stream>>>(x, ph, pl,
                                      (float*)XB1, nullptr, 64, 1,
                                      HCAT + 64, bl1, 128, 0, 0);
    gather_kernel<64, 1, 1><<<12500, 256, 0, stream>>>(
        XB1, 64, srcs, off, cnt, inv, HCAT + 64, 128, HCAT + 64, 128, H1B);

    // ---- Layer 2: mean(H1B) -> HCAT cols 0..63; [mean|h1]@[Wl2|Wr2] -> H2 (relu) ----
    gather_kernel<64, 0, 0><<<12500, 256, 0, stream>>>(
        H1B, 64, srcs, off, cnt, inv, nullptr, 0, HCAT, 128, nullptr);
    gemm_mfma<<<GB, 256, 0, stream>>>(HCAT, ph + 16384, pl + 16384,
                                      H2, bl2, 128, 0,
                                      H2 + 64, bl2 + 64, 128, 0, 1);

    // ---- Layer 3: h2@Wl3 -> G3B (bf16); h2@Wr3+bl3 -> h3pre(=HPRE fp32) ----
    gemm_mfma<<<GB, 256, 0, stream>>>(H2, ph + 2 * 16384, pl + 2 * 16384,
                                      (float*)G3B, nullptr, 128, 1,
                                      (float*)(G3B + 64), nullptr, 128, 1, 0);
    gemm_mfma<<<GB, 256, 0, stream>>>(H2, ph + 3 * 16384, pl + 3 * 16384,
                                      HPRE, bl3, 128, 0,
                                      HPRE + 64, bl3 + 64, 128, 0, 0);
    gather_kernel<128, 1, 0><<<12500, 256, 0, stream>>>(
        G3B, 128, srcs, off, cnt, inv, HPRE, 128, HPRE, 128, nullptr);

    // ---- Layer 4: h3@Wl4 -> G4B (bf16); h3@Wr4+bl4 -> d_out; gather -> out ----
    gemm_mfma<<<GB, 256, 0, stream>>>(HPRE, ph + 4 * 16384, pl + 4 * 16384,
                                      (float*)G4B, nullptr, 64, 1,
                                      out, bl4, 64, 0, 0);
    gather_kernel<64, 2, 0><<<12500, 256, 0, stream>>>(
        G4B, 64, srcs, off, cnt, inv, out, 64, out, 64, nullptr);
}